// Round 13
// baseline (2371.964 us; speedup 1.0000x reference)
//
#include <hip/hip_runtime.h>
#include <hip/hip_bf16.h>
#include <cstdint>

typedef _Float16 h2 __attribute__((ext_vector_type(2)));
typedef _Float16 h4 __attribute__((ext_vector_type(4)));
typedef _Float16 h8 __attribute__((ext_vector_type(8)));
typedef float f4 __attribute__((ext_vector_type(4)));
typedef unsigned long long u64;
typedef unsigned int u32;

#define S_LEN 512
#define BATCH 64
#define DM    512
#define HID   768

union h4u { u64 u; h4 v; };

static __device__ __forceinline__ h8 pack8(float4 a, float4 b) {
  h8 v;
  v[0] = (_Float16)a.x; v[1] = (_Float16)a.y;
  v[2] = (_Float16)a.z; v[3] = (_Float16)a.w;
  v[4] = (_Float16)b.x; v[5] = (_Float16)b.y;
  v[6] = (_Float16)b.z; v[7] = (_Float16)b.w;
  return v;
}

// swizzled LDS access for [row][64 k] fp16 tiles (row stride 128B)
static __device__ __forceinline__ h8 ldfrag(const _Float16* S, int row, int ke) {
  int byte = (row << 7) + (ke << 1);
  byte ^= (row & 7) << 4;
  return *(const h8*)((const char*)S + byte);
}
static __device__ __forceinline__ void stfrag(_Float16* S, int row, int ke, h8 v) {
  int byte = (row << 7) + (ke << 1);
  byte ^= (row & 7) << 4;
  *(h8*)((char*)S + byte) = v;
}

// ---------------------------------------------------------------------------
// gemm body (device): xg[dir] = gather(emb, ids) @ Wi^T + bi  -> fp16 xg
// smem layout: Ws [0,16384), Es [16384,32768), ids [32768,33280)
// ---------------------------------------------------------------------------
static __device__ void gemm_body(
    unsigned char* smem, int mt, int nt, int dir,
    const int* __restrict__ ids, const float* __restrict__ emb,
    const float* __restrict__ Wi_f, const float* __restrict__ bi_f,
    const float* __restrict__ Wi_b, const float* __restrict__ bi_b,
    int s0_f, int s0_b,
    _Float16* __restrict__ xg_f, _Float16* __restrict__ xg_b)
{
  const float* __restrict__ Wi = dir ? Wi_b : Wi_f;
  const float* __restrict__ bi = dir ? bi_b : bi_f;
  _Float16*   __restrict__ xg  = dir ? xg_b : xg_f;
  const int s0 = dir ? s0_b : s0_f;

  _Float16* Ws = (_Float16*)smem;
  _Float16* Es = (_Float16*)(smem + 16384);
  int* ids_s   = (int*)(smem + 32768);

  const int tid = threadIdx.x;
  if (tid < 128) {
    ids_s[tid] = ids[(tid & 63) * S_LEN + s0 + mt * 2 + (tid >> 6)];
  }

  const int w  = tid >> 6;          // wave 0..3
  const int L  = tid & 63;
  const int lh = L >> 4;            // 0..3
  const int ln = L & 15;            // 0..15
  const int wn = (w >> 1) * 64;     // wave n-base
  const int wm = (w & 1) * 64;      // wave m-base

  const int r  = tid >> 1;          // staging row 0..127
  const int kh = (tid & 1) * 32;    // staging k offset

  f4 acc[4][4];
#pragma unroll
  for (int i = 0; i < 4; ++i)
#pragma unroll
    for (int j = 0; j < 4; ++j) { acc[i][j][0]=0.f; acc[i][j][1]=0.f; acc[i][j][2]=0.f; acc[i][j][3]=0.f; }

  __syncthreads();

  for (int kt = 0; kt < DM; kt += 64) {
    {
      const float* srcW = Wi + (size_t)(nt * 128 + r) * DM + kt + kh;
      const float* srcE = emb + (size_t)ids_s[r] * DM + kt + kh;
      float4 w0 = ((const float4*)srcW)[0], w1 = ((const float4*)srcW)[1];
      float4 w2 = ((const float4*)srcW)[2], w3 = ((const float4*)srcW)[3];
      float4 w4 = ((const float4*)srcW)[4], w5 = ((const float4*)srcW)[5];
      float4 w6 = ((const float4*)srcW)[6], w7 = ((const float4*)srcW)[7];
      float4 e0 = ((const float4*)srcE)[0], e1 = ((const float4*)srcE)[1];
      float4 e2 = ((const float4*)srcE)[2], e3 = ((const float4*)srcE)[3];
      float4 e4 = ((const float4*)srcE)[4], e5 = ((const float4*)srcE)[5];
      float4 e6 = ((const float4*)srcE)[6], e7 = ((const float4*)srcE)[7];
      stfrag(Ws, r, kh + 0,  pack8(w0, w1));
      stfrag(Ws, r, kh + 8,  pack8(w2, w3));
      stfrag(Ws, r, kh + 16, pack8(w4, w5));
      stfrag(Ws, r, kh + 24, pack8(w6, w7));
      stfrag(Es, r, kh + 0,  pack8(e0, e1));
      stfrag(Es, r, kh + 8,  pack8(e2, e3));
      stfrag(Es, r, kh + 16, pack8(e4, e5));
      stfrag(Es, r, kh + 24, pack8(e6, e7));
    }
    __syncthreads();
#pragma unroll
    for (int ks = 0; ks < 2; ++ks) {
      h8 af[4], bf[4];
#pragma unroll
      for (int i = 0; i < 4; ++i) af[i] = ldfrag(Ws, wn + i * 16 + ln, ks * 32 + lh * 8);
#pragma unroll
      for (int j = 0; j < 4; ++j) bf[j] = ldfrag(Es, wm + j * 16 + ln, ks * 32 + lh * 8);
#pragma unroll
      for (int i = 0; i < 4; ++i)
#pragma unroll
        for (int j = 0; j < 4; ++j)
          acc[i][j] = __builtin_amdgcn_mfma_f32_16x16x32_f16(af[i], bf[j], acc[i][j], 0, 0, 0);
    }
    __syncthreads();
  }

#pragma unroll
  for (int i = 0; i < 4; ++i) {
    const int n_g = nt * 128 + wn + i * 16 + lh * 4;
    const int gate = n_g / 768;
    const int jj = n_g - gate * 768;
    const f4 bv = *(const f4*)&bi[n_g];
#pragma unroll
    for (int j = 0; j < 4; ++j) {
      const int m = mt * 128 + wm + j * 16 + ln;
      const int sl = m >> 6, b = m & 63;
      h4 v;
#pragma unroll
      for (int rr = 0; rr < 4; ++rr) v[rr] = (_Float16)(acc[i][j][rr] + bv[rr]);
      *(h4*)&xg[(((size_t)sl * 3 + gate) * 64 + b) * 768 + jj] = v;
    }
  }
}

// standalone gemm (chunk 0): full occupancy
__global__ __launch_bounds__(256) void gemm1_kernel(
    const int* __restrict__ ids, const float* __restrict__ emb,
    const float* __restrict__ Wi_f, const float* __restrict__ bi_f,
    const float* __restrict__ Wi_b, const float* __restrict__ bi_b,
    int s0_f, int s0_b,
    _Float16* __restrict__ xg_f, _Float16* __restrict__ xg_b)
{
  __shared__ __align__(16) unsigned char smem[33280];
  gemm_body(smem, blockIdx.x, blockIdx.y, blockIdx.z,
            ids, emb, Wi_f, bi_f, Wi_b, bi_b, s0_f, s0_b, xg_f, xg_b);
}

// ---------------------------------------------------------------------------
// scan body (device): MFMA GRU scan, value-embedded tags, double-buffered LDS.
// smem: hs[2][24576). One __syncthreads per step (stage->MFMA). The tag
// protocol bounds wave skew: poll(t+2) can't pass until own block stored t+1,
// and the collective sync bounds divergence to one iteration segment.
// Poll has s_sleep backoff to cut device-scope load congestion.
// ---------------------------------------------------------------------------
static __device__ void scan_body(
    unsigned char* hs0, int blk,
    const float* __restrict__ Wh_f, const float* __restrict__ bh_f,
    const float* __restrict__ Wh_b, const float* __restrict__ bh_b,
    const _Float16* __restrict__ xg_f, const _Float16* __restrict__ xg_b,
    char* __restrict__ hx, float* __restrict__ hfin,
    int step0, int nsteps)
{
  const int dir = blk / 48;
  const int l   = blk - dir * 48;   // 0..47
  const int bg  = l / 12;           // batch group 0..3
  const int jb  = l - bg * 12;      // unit twelfth 0..11

  const float* __restrict__ Wh = dir ? Wh_b : Wh_f;
  const float* __restrict__ bh = dir ? bh_b : bh_f;
  const _Float16* __restrict__ xg = dir ? xg_b : xg_f;
  char*  payB = hx + (size_t)dir * 2 * 64 * 1536;
  float* hfd  = hfin + (size_t)dir * 64 * 768;

  const int tid = threadIdx.x;
  const int w   = tid >> 6;         // wave 0..3
  const int L   = tid & 63;
  const int lh  = L >> 4;           // 0..3
  const int ln  = L & 15;           // 0..15
  const int jt  = jb * 4 + w;       // unit tile 0..47
  const int jrow = jt * 16 + ln;    // A-fragment row (j)
  const int j0l  = jt * 16 + lh * 4;  // 4 owned units
  const int bglob = bg * 16 + ln;   // owned batch column (producer)
  const int bb  = tid >> 4;         // consumer batch row 0..15
  const int qi  = tid & 15;         // consumer pair-group base

  // ---- Wh as A-fragments
  h8 A[3][24];
#pragma unroll
  for (int g = 0; g < 3; ++g)
#pragma unroll
    for (int ks = 0; ks < 24; ++ks) {
      const float* src = Wh + (size_t)(g * 768 + jrow) * 768 + ks * 32 + lh * 8;
      float4 w0 = ((const float4*)src)[0];
      float4 w1 = ((const float4*)src)[1];
      A[g][ks] = pack8(w0, w1);
    }

  f4 bhv[3];
#pragma unroll
  for (int g = 0; g < 3; ++g) bhv[g] = *(const f4*)&bh[g * 768 + j0l];

  // ---- fp32 h master
  f4 hm;
  if (step0 == 0) { hm[0]=0.f; hm[1]=0.f; hm[2]=0.f; hm[3]=0.f; }
  else {
    const float* src = &hfd[(size_t)bglob * 768 + j0l];
    asm volatile("global_load_dwordx4 %0, %1, off sc0 sc1\n\t"
                 "s_waitcnt vmcnt(0)"
                 : "=&v"(hm) : "v"(src) : "memory");
  }

  // producer slot: batch bglob, granule jt*4+lh (4 units), 8B
  char* const pslot = payB + (size_t)bglob * 1536 + (size_t)(jt * 4 + lh) * 8;
  // consumer: batch bb, pair p = qi+16*i at byte qi*16 + 256*i
  const char* const crow = payB + (size_t)(bg * 16 + bb) * 1536 + qi * 16;
  const int swb = (bb ^ (qi & 7)) * 16;   // swizzled LDS column (row&7==qi&7)

  for (int t = 0; t < nsteps; ++t) {
    const int sg = step0 + t;
    const int pin = sg & 1, pout = pin ^ 1;
    unsigned char* hs = hs0 + (size_t)(sg & 1) * 24576;   // LDS double buffer

    // xg loads for this step (overlap the poll's vmcnt)
    const int lsl = dir ? (nsteps - 1 - t) : t;
    const _Float16* xrow = xg + (((size_t)lsl * 3) * 64 + bglob) * 768 + j0l;
    h4 xr4 = *(const h4*)xrow;
    h4 xz4 = *(const h4*)(xrow + (size_t)64 * 768);
    h4 xn4 = *(const h4*)(xrow + (size_t)2 * 64 * 768);

    // ---- poll payload until all 12 embedded tags == sg&15 (sleep backoff)
    const u32 texp = (u32)sg & 15u;
    const u32 e0 = ((texp & 1u) << 14) | ((texp & 2u) << 29);
    const u32 e1 = ((texp & 4u) << 12) | ((texp & 8u) << 27);
    const char* pc = crow + (size_t)pin * 64 * 1536;
    u64 q0,q1,q2,q3,q4,q5,q6,q7,q8,q9,q10,q11;
    for (int spin = 0;; ++spin) {
      asm volatile(
        "global_load_dwordx2 %0, %12, off sc0 sc1\n\t"
        "global_load_dwordx2 %1, %12, off offset:8 sc0 sc1\n\t"
        "global_load_dwordx2 %2, %13, off sc0 sc1\n\t"
        "global_load_dwordx2 %3, %13, off offset:8 sc0 sc1\n\t"
        "global_load_dwordx2 %4, %14, off sc0 sc1\n\t"
        "global_load_dwordx2 %5, %14, off offset:8 sc0 sc1\n\t"
        "global_load_dwordx2 %6, %15, off sc0 sc1\n\t"
        "global_load_dwordx2 %7, %15, off offset:8 sc0 sc1\n\t"
        "global_load_dwordx2 %8, %16, off sc0 sc1\n\t"
        "global_load_dwordx2 %9, %16, off offset:8 sc0 sc1\n\t"
        "global_load_dwordx2 %10, %17, off sc0 sc1\n\t"
        "global_load_dwordx2 %11, %17, off offset:8 sc0 sc1\n\t"
        "s_waitcnt vmcnt(0)"
        : "=&v"(q0), "=&v"(q1), "=&v"(q2), "=&v"(q3), "=&v"(q4), "=&v"(q5),
          "=&v"(q6), "=&v"(q7), "=&v"(q8), "=&v"(q9), "=&v"(q10), "=&v"(q11)
        : "v"(pc), "v"(pc + 256), "v"(pc + 512),
          "v"(pc + 768), "v"(pc + 1024), "v"(pc + 1280)
        : "memory");
      u32 bad = 0;
      u64 qs[12] = {q0,q1,q2,q3,q4,q5,q6,q7,q8,q9,q10,q11};
#pragma unroll
      for (int i = 0; i < 12; ++i) {
        u32 lo = (u32)qs[i], hi = (u32)(qs[i] >> 32);
        bad |= ((lo & 0x40004000u) ^ e0) | ((hi & 0x40004000u) ^ e1);
      }
      if (bad == 0) break;
      asm volatile("s_sleep 2");          // ~128 cyc backoff vs LLC congestion
    }
    // clear tag bits and stage to LDS (pair rows qi+16i, swizzled col)
    {
      const u64 CM = 0xBFFFBFFFBFFFBFFFull;
      u64 qa[12] = {q0&CM,q1&CM,q2&CM,q3&CM,q4&CM,q5&CM,q6&CM,q7&CM,q8&CM,q9&CM,q10&CM,q11&CM};
#pragma unroll
      for (int i = 0; i < 6; ++i) {
        u64* d = (u64*)(hs + (qi + 16 * i) * 256 + swb);
        d[0] = qa[2 * i];
        d[1] = qa[2 * i + 1];
      }
    }
    __syncthreads();   // the single per-step barrier: stage -> MFMA

    // ---- B-fragments from LDS + MFMA  (pair row p = ks*4+lh)
    f4 Cr, Cz, Cn;
    Cr[0]=0.f;Cr[1]=0.f;Cr[2]=0.f;Cr[3]=0.f;
    Cz = Cr; Cn = Cr;
#pragma unroll
    for (int ks = 0; ks < 24; ++ks) {
      const int p = ks * 4 + lh;
      h8 Bf = *(const h8*)(hs + p * 256 + ((ln ^ (p & 7)) * 16));
      Cr = __builtin_amdgcn_mfma_f32_16x16x32_f16(A[0][ks], Bf, Cr, 0, 0, 0);
      Cz = __builtin_amdgcn_mfma_f32_16x16x32_f16(A[1][ks], Bf, Cz, 0, 0, 0);
      Cn = __builtin_amdgcn_mfma_f32_16x16x32_f16(A[2][ks], Bf, Cn, 0, 0, 0);
    }

    // ---- gates
    f4 hnew;
    h4u st;
#pragma unroll
    for (int r = 0; r < 4; ++r) {
      float rr = 1.f / (1.f + __expf(-((float)xr4[r] + Cr[r] + bhv[0][r])));
      float zz = 1.f / (1.f + __expf(-((float)xz4[r] + Cz[r] + bhv[1][r])));
      float nn = tanhf((float)xn4[r] + rr * (Cn[r] + bhv[2][r]));
      hnew[r] = (1.f - zz) * nn + zz * hm[r];
      st.v[r] = (_Float16)fminf(1.f, fmaxf(-1.f, hnew[r]));
    }
    hm = hnew;

    // ---- producer: embed tag (sg+1)&15 in bit14s, single 8B store
    {
      const u32 tw = (u32)(sg + 1) & 15u;
      u32 lo = (u32)st.u, hi = (u32)(st.u >> 32);
      lo |= ((tw & 1u) << 14) | ((tw & 2u) << 29);
      hi |= ((tw & 4u) << 12) | ((tw & 8u) << 27);
      u64 pv = ((u64)hi << 32) | lo;
      char* dst = pslot + (size_t)pout * 64 * 1536;
      asm volatile("global_store_dwordx2 %0, %1, off sc0 sc1"
                   :: "v"(dst), "v"(pv) : "memory");
    }
    // no end-of-loop barrier: LDS double buffer + tag protocol bound skew
  }

  // chunk-save fp32 h
  {
    float* dst = &hfd[(size_t)bglob * 768 + j0l];
    asm volatile("global_store_dwordx4 %0, %1, off sc0 sc1"
                 :: "v"(dst), "v"(hm) : "memory");
  }
}

// ---------------------------------------------------------------------------
// Fused kernel: blocks 0..95 scan chunk c; blocks 96.. gemm chunk c+1.
// gemm blocks never wait (always retire); scan blocks dispatched first and
// only wait on each other -> co-residency guaranteed.
// ---------------------------------------------------------------------------
__global__ __launch_bounds__(256, 1) void fused_kernel(
    const float* __restrict__ Wh_f, const float* __restrict__ bh_f,
    const float* __restrict__ Wh_b, const float* __restrict__ bh_b,
    const _Float16* __restrict__ sxg_f, const _Float16* __restrict__ sxg_b,
    char* __restrict__ hx, float* __restrict__ hfin, int step0, int nsteps,
    const int* __restrict__ ids, const float* __restrict__ emb,
    const float* __restrict__ Wi_f, const float* __restrict__ bi_f,
    const float* __restrict__ Wi_b, const float* __restrict__ bi_b,
    int g_s0f, int g_s0b,
    _Float16* __restrict__ gxg_f, _Float16* __restrict__ gxg_b, int mtc)
{
  __shared__ __align__(16) unsigned char smem[49152];
  const int b = blockIdx.x;
  if (b < 96) {
    scan_body(smem, b, Wh_f, bh_f, Wh_b, bh_b, sxg_f, sxg_b,
              hx, hfin, step0, nsteps);
  } else {
    const int e = b - 96;
    const int mt = e % mtc;
    const int r2 = e / mtc;
    const int nt = r2 % 18;
    const int dir = r2 / 18;
    gemm_body(smem, mt, nt, dir, ids, emb, Wi_f, bi_f, Wi_b, bi_b,
              g_s0f, g_s0b, gxg_f, gxg_b);
  }
}

// ---------------------------------------------------------------------------
// MLP head.  hfin layout: [dir][b][j] fp32.
// ---------------------------------------------------------------------------
__global__ __launch_bounds__(256) void mlp1_kernel(
    const float* __restrict__ hfin, const float* __restrict__ W1,
    const float* __restrict__ b1, float* __restrict__ hid)
{
  const int c = blockIdx.x * 4 + (threadIdx.x >> 6);
  const int b = threadIdx.x & 63;
  const float* __restrict__ hf = hfin + (size_t)b * 768;
  const float* __restrict__ hb = hfin + (size_t)(64 + b) * 768;
  const float* __restrict__ w = W1 + (size_t)c * 1536;
  float acc = b1[c];
  for (int k = 0; k < 768; k += 4) {
    float4 hv = *(const float4*)&hf[k];
    float4 wv = *(const float4*)&w[k];
    acc += hv.x * wv.x + hv.y * wv.y + hv.z * wv.z + hv.w * wv.w;
  }
  for (int k = 0; k < 768; k += 4) {
    float4 hv = *(const float4*)&hb[k];
    float4 wv = *(const float4*)&w[768 + k];
    acc += hv.x * wv.x + hv.y * wv.y + hv.z * wv.z + hv.w * wv.w;
  }
  hid[(size_t)c * 64 + b] = fmaxf(acc, 0.f);
}

__global__ void mlp2_kernel(const float* __restrict__ hid,
                            const float* __restrict__ W2,
                            const float* __restrict__ b2,
                            float* __restrict__ out)
{
  const int tid = threadIdx.x;      // 128 threads
  const int b = tid & 63, cls = tid >> 6;
  const float* __restrict__ w = W2 + cls * 768;
  float acc = b2[cls];
  for (int k = 0; k < 768; ++k) acc += hid[(size_t)k * 64 + b] * w[k];
  out[b * 2 + cls] = acc;
}

// ---------------------------------------------------------------------------
extern "C" void kernel_launch(void* const* d_in, const int* in_sizes, int n_in,
                              void* d_out, int out_size, void* d_ws, size_t ws_size,
                              hipStream_t stream)
{
  const int*   ids  = (const int*)d_in[0];
  const float* emb  = (const float*)d_in[1];
  const float* Wi_f = (const float*)d_in[2];
  const float* Wh_f = (const float*)d_in[3];
  const float* bi_f = (const float*)d_in[4];
  const float* bh_f = (const float*)d_in[5];
  const float* Wi_b = (const float*)d_in[6];
  const float* Wh_b = (const float*)d_in[7];
  const float* bi_b = (const float*)d_in[8];
  const float* bh_b = (const float*)d_in[9];
  const float* W1   = (const float*)d_in[10];
  const float* b1   = (const float*)d_in[11];
  const float* W2   = (const float*)d_in[12];
  const float* b2   = (const float*)d_in[13];
  float* out = (float*)d_out;

  // state sizes (bytes)
  const size_t B_HX   = (size_t)2 * 2 * 64 * 1536;      // 393216
  const size_t B_HFIN = (size_t)2 * 64 * 768 * 4;       // 393216
  const size_t B_HID  = (size_t)HID * BATCH * 4;        // 196608
  const size_t state_bytes = B_HX + B_HFIN + B_HID;

  // choose chunk size: largest CH with DOUBLE-buffered xg + state <= ws
  int CH = 512;
  while (CH > 8) {
    size_t need = (size_t)8 * CH * 64 * 2304 + state_bytes;
    if (need <= ws_size) break;
    CH >>= 1;
  }
  const size_t SZ_XG = (size_t)CH * 64 * 2304;      // halves per dir per buf

  char* ws = (char*)d_ws;
  _Float16* xgbuf0 = (_Float16*)ws;                 // buf0: [f][b]
  _Float16* xgbuf1 = xgbuf0 + 2 * SZ_XG;            // buf1: [f][b]
  char*     hx   = (char*)(xgbuf1 + 2 * SZ_XG);
  float*    hfin = (float*)(hx + B_HX);
  float*    hid  = (float*)((char*)hfin + B_HFIN);

  // zero hx + hfin + hid (contiguous) every call
  (void)hipMemsetAsync(hx, 0, state_bytes, stream);

  const int nch = 512 / CH;
  // chunk 0 gemm at full occupancy
  gemm1_kernel<<<dim3(CH / 2, 18, 2), 256, 0, stream>>>(
      ids, emb, Wi_f, bi_f, Wi_b, bi_b, 0, 512 - CH, xgbuf0, xgbuf0 + SZ_XG);

  for (int c = 0; c < nch; ++c) {
    _Float16* sf = (c & 1) ? xgbuf1 : xgbuf0;
    _Float16* gf = (c & 1) ? xgbuf0 : xgbuf1;
    const int ng = (c + 1 < nch) ? (CH / 2) * 36 : 0;
    fused_kernel<<<96 + ng, 256, 0, stream>>>(
        Wh_f, bh_f, Wh_b, bh_b, sf, sf + SZ_XG, hx, hfin, c * CH, CH,
        ids, emb, Wi_f, bi_f, Wi_b, bi_b,
        (c + 1) * CH, 512 - (c + 2) * CH, gf, gf + SZ_XG, CH / 2);
  }
  mlp1_kernel<<<192, 256, 0, stream>>>(hfin, W1, b1, hid);
  mlp2_kernel<<<1, 128, 0, stream>>>(hid, W2, b2, out);
}